// Round 1
// baseline (1414.876 us; speedup 1.0000x reference)
//
#include <hip/hip_runtime.h>
#include <cstdint>
#include <cstddef>

#define B_ 512
#define T_ 2048
#define D_ 64
#define H_ 48
#define C_ 3
#define TT 32
#define NTHREADS 256

__global__ __launch_bounds__(NTHREADS, 2) void snn_fused(
    const float* __restrict__ x,
    const float* __restrict__ Wenc, const float* __restrict__ benc,
    const float* __restrict__ Wmem, const float* __restrict__ bmem,
    const float* __restrict__ Wdec, const float* __restrict__ bdec,
    const float* __restrict__ Wcls, const float* __restrict__ bcls,
    float* __restrict__ out)
{
    // padded leading dims to break LDS bank alignment (4h mod 32 spread)
    __shared__ float sWenc[H_][68];   // W_enc[h][d]
    __shared__ float sWdec[D_][52];   // W_dec[d][h]
    __shared__ float sbenc[H_];
    __shared__ float sbdec[D_];
    __shared__ float sx[TT][68];      // x tile [s][d]
    __shared__ float su[TT][H_];      // u tile [s][h]
    __shared__ float sz[TT][H_];      // z tile [s][h]
    __shared__ float smem[H_];        // recurrent state
    __shared__ float szsum[H_];

    const int tid = threadIdx.x;
    const int b   = blockIdx.x;

    // ---- stage weights (coalesced) ----
    for (int idx = tid; idx < H_ * D_; idx += NTHREADS) {
        int h = idx >> 6, d = idx & 63;
        sWenc[h][d] = Wenc[idx];
    }
    for (int idx = tid; idx < D_ * H_; idx += NTHREADS) {
        int d = idx / H_, h = idx - d * H_;
        sWdec[d][h] = Wdec[idx];
    }
    if (tid < H_) sbenc[tid] = benc[tid];
    if (tid < D_) sbdec[tid] = bdec[tid];
    if (tid < H_) smem[tid] = 0.0f;

    // wave-0 lanes (<48) own one row of W_mem in registers + recurrent state
    float wm[H_];
    float bm = 0.0f, memreg = 0.0f, zs = 0.0f;
    if (tid < H_) {
        #pragma unroll
        for (int j = 0; j < H_; ++j) wm[j] = Wmem[tid * H_ + j];
        bm = bmem[tid];
    }
    __syncthreads();

    float*       reconb = out + (size_t)b * T_ * D_;
    float*       logitg = out + (size_t)B_ * T_ * D_;
    float*       zb     = out + (size_t)B_ * T_ * D_ + (size_t)B_ * C_
                              + (size_t)b * T_ * H_;
    const float* xb     = x + (size_t)b * T_ * D_;

    for (int t0 = 0; t0 < T_; t0 += TT) {
        // ---- load x tile (float4, coalesced) ----
        for (int k = tid; k < TT * (D_ / 4); k += NTHREADS) {
            int s = k >> 4, d4 = k & 15;
            float4 v = *reinterpret_cast<const float4*>(xb + (size_t)(t0 + s) * D_ + d4 * 4);
            *reinterpret_cast<float4*>(&sx[s][d4 * 4]) = v;
        }
        __syncthreads();

        // ---- encoder: u[s][h] = b_enc[h] + x[s][:] . W_enc[h][:]  (6 outputs/thread) ----
        #pragma unroll
        for (int k = 0; k < (TT * H_) / NTHREADS; ++k) {
            int o = tid + k * NTHREADS;
            int s = o / H_, h = o - s * H_;
            const float* xr = sx[s];
            const float* wr = sWenc[h];
            float a0 = 0.f, a1 = 0.f, a2 = 0.f, a3 = 0.f;
            #pragma unroll
            for (int d = 0; d < D_; d += 4) {
                float4 xv = *reinterpret_cast<const float4*>(xr + d);
                float4 wv = *reinterpret_cast<const float4*>(wr + d);
                a0 += xv.x * wv.x; a1 += xv.y * wv.y;
                a2 += xv.z * wv.z; a3 += xv.w * wv.w;
            }
            su[s][h] = sbenc[h] + ((a0 + a1) + (a2 + a3));
        }
        __syncthreads();

        // ---- recurrence: wave 0, lanes < 48, sequential over the 32 steps ----
        if (tid < H_) {
            for (int s = 0; s < TT; ++s) {
                float cur = su[s][tid] + bm;
                #pragma unroll
                for (int j4 = 0; j4 < H_ / 4; ++j4) {
                    float4 m = *reinterpret_cast<const float4*>(&smem[j4 * 4]);
                    cur += m.x * wm[4 * j4 + 0] + m.y * wm[4 * j4 + 1]
                         + m.z * wm[4 * j4 + 2] + m.w * wm[4 * j4 + 3];
                }
                memreg = 0.9f * memreg + 0.1f * cur;
                smem[tid] = memreg;
                float zz = 1.0f / (1.0f + __expf(-memreg));
                sz[s][tid] = zz;
                zs += zz;
            }
        }
        __syncthreads();

        // ---- decoder: recon[s][d] = b_dec[d] + z[s][:] . W_dec[d][:]  (8 outputs/thread) ----
        #pragma unroll
        for (int k = 0; k < (TT * D_) / NTHREADS; ++k) {
            int o = tid + k * NTHREADS;
            int s = o >> 6, d = o & 63;
            const float* zr = sz[s];
            const float* wr = sWdec[d];
            float a0 = 0.f, a1 = 0.f, a2 = 0.f, a3 = 0.f;
            #pragma unroll
            for (int h = 0; h < H_; h += 4) {
                float4 zv = *reinterpret_cast<const float4*>(zr + h);
                float4 wv = *reinterpret_cast<const float4*>(wr + h);
                a0 += zv.x * wv.x; a1 += zv.y * wv.y;
                a2 += zv.z * wv.z; a3 += zv.w * wv.w;
            }
            reconb[(size_t)(t0 + s) * D_ + d] = sbdec[d] + ((a0 + a1) + (a2 + a3));
        }
        // ---- z tile store (contiguous float4) ----
        for (int k = tid; k < (TT * H_) / 4; k += NTHREADS) {
            float4 v = *reinterpret_cast<const float4*>(&sz[0][0] + (size_t)k * 4);
            *reinterpret_cast<float4*>(zb + (size_t)t0 * H_ + (size_t)k * 4) = v;
        }
        __syncthreads();  // sz/su/sx reuse next tile; doubles as store-complete barrier
    }

    // ---- classifier head ----
    if (tid < H_) szsum[tid] = zs;
    __syncthreads();
    if (tid < C_) {
        float acc = 0.0f;
        #pragma unroll
        for (int h = 0; h < H_; ++h) acc += szsum[h] * Wcls[tid * H_ + h];
        logitg[(size_t)b * C_ + tid] = acc * (1.0f / (float)T_) + bcls[tid];
    }
}

extern "C" void kernel_launch(void* const* d_in, const int* in_sizes, int n_in,
                              void* d_out, int out_size, void* d_ws, size_t ws_size,
                              hipStream_t stream) {
    const float* x    = (const float*)d_in[0];
    const float* Wenc = (const float*)d_in[1];
    const float* benc = (const float*)d_in[2];
    const float* Wmem = (const float*)d_in[3];
    const float* bmem = (const float*)d_in[4];
    const float* Wdec = (const float*)d_in[5];
    const float* bdec = (const float*)d_in[6];
    const float* Wcls = (const float*)d_in[7];
    const float* bcls = (const float*)d_in[8];

    snn_fused<<<dim3(B_), dim3(NTHREADS), 0, stream>>>(
        x, Wenc, benc, Wmem, bmem, Wdec, bdec, Wcls, bcls, (float*)d_out);
}